// Round 13
// baseline (294.073 us; speedup 1.0000x reference)
//
#include <hip/hip_runtime.h>

#define DD   256
#define TT   1024
#define BT   8192
#define KK   8192
#define ZQ_SIZE 2097152

#define FLT_INF 3.402823466e38f

typedef __attribute__((ext_vector_type(8))) short short8;
typedef __attribute__((ext_vector_type(4))) float f32x4;

// ws layout (bytes)
// A2/B2: fragment-stream packing. 1024-B block per (16-row group, part, 32-k chunk):
//   short at blockbase + lane*8 + j holds X[row = grp*16 + (lane&15)][k = kk*32 + (lane>>4)*8 + j]
// A2[g 0..511][p 0..2][kk 0..7] ; B2[ng 0..511][p][kk]
#define A2_B    0u           // 512*3*8*1024 = 12582912 B
#define B2_B    12582912u
#define AN_B    25165824u    // An: 8192 f32
#define CN_B    25198592u    // Cn: 8192 f32
#define KEY_B   25231360u    // keys: 8192 u64
#define ACC_B   25296896u    // loss acc: 1 f32

static __device__ __forceinline__ unsigned short f2bf(float x) {  // RNE fp32->bf16
    unsigned int u = __float_as_uint(x);
    return (unsigned short)((u + 0x7FFF + ((u >> 16) & 1)) >> 16);
}
static __device__ __forceinline__ float bf2f(unsigned short h) {
    return __uint_as_float(((unsigned int)h) << 16);
}
// exact 3-term split: x == h + m + l (each difference exact in fp32)
static __device__ __forceinline__ void split3(float x, unsigned short& h,
                                              unsigned short& m, unsigned short& l) {
    h = f2bf(x);
    float r1 = x - bf2f(h);
    m = f2bf(r1);
    l = f2bf(r1 - bf2f(m));
}

// ---------------- kernel 1: fused prep ----------------
// blocks 0..2047:    B2 frag-pack + Cn + keys/lacc init
// blocks 2048..2175: A2 frag-pack (via LDS transpose) + An (token norms)
__global__ __launch_bounds__(256) void vq_prep(const float* __restrict__ z,
                                               const float* __restrict__ cb,
                                               float* __restrict__ An,
                                               unsigned short* __restrict__ A2,
                                               unsigned short* __restrict__ B2,
                                               float* __restrict__ Cn,
                                               unsigned long long* __restrict__ keys,
                                               float* __restrict__ lacc) {
    __shared__ float T[64][257];
    int tid = threadIdx.x;
    if (blockIdx.x < 2048) {
        // B2: cb -> fragment-stream packing ; Cn fused ; keys init fused
        int g = blockIdx.x * 256 + tid;              // 0..524287
        int code = g >> 6, d4 = (g & 63) * 4;
        if (d4 == 0) {
            keys[code] = ~0ull;
            if (code == 0) *lacc = 0.f;
        }
        float4 v = *(const float4*)&cb[(size_t)code * DD + d4];
        unsigned short h[4], m[4], l[4];
        split3(v.x, h[0], m[0], l[0]);
        split3(v.y, h[1], m[1], l[1]);
        split3(v.z, h[2], m[2], l[2]);
        split3(v.w, h[3], m[3], l[3]);
        int ng = code >> 4;
        int lane = ((d4 >> 3) & 3) * 16 + (code & 15);
        int kk = d4 >> 5;
        int jb = d4 & 7;                             // 0 or 4
        size_t base = (size_t)((ng * 3) * 8 + kk) * 512 + lane * 8 + jb;
        *(ushort4*)&B2[base]        = make_ushort4(h[0], h[1], h[2], h[3]);
        *(ushort4*)&B2[base + 4096] = make_ushort4(m[0], m[1], m[2], m[3]);
        *(ushort4*)&B2[base + 8192] = make_ushort4(l[0], l[1], l[2], l[3]);
        float s = v.x * v.x + v.y * v.y + v.z * v.z + v.w * v.w;
        #pragma unroll
        for (int off = 32; off; off >>= 1) s += __shfl_down(s, off, 64);
        if ((tid & 63) == 0) Cn[code] = s;
    } else {
        // A2 via LDS transpose: z[b,d,t] -> frag-stream packing ; An fused
        int blk = blockIdx.x - 2048;                 // 0..127
        int b = blk >> 4;
        int t0 = (blk & 15) * 64;
        #pragma unroll
        for (int it = 0; it < 16; ++it) {
            int d = it * 16 + (tid >> 4);
            int t4 = (tid & 15) * 4;
            float4 v = *(const float4*)&z[(size_t)b * (DD * TT) + (size_t)d * TT + t0 + t4];
            T[t4 + 0][d] = v.x; T[t4 + 1][d] = v.y; T[t4 + 2][d] = v.z; T[t4 + 3][d] = v.w;
        }
        __syncthreads();
        int r = tid >> 2, q = tid & 3;
        int t = b * 1024 + t0 + r;
        int gA = t >> 4, ml = t & 15;
        float s = 0.f;
        #pragma unroll
        for (int dd = 0; dd < 16; ++dd) {
            int d = dd * 16 + q * 4;
            float v0 = T[r][d], v1 = T[r][d + 1], v2 = T[r][d + 2], v3 = T[r][d + 3];
            unsigned short h[4], m[4], l[4];
            split3(v0, h[0], m[0], l[0]);
            split3(v1, h[1], m[1], l[1]);
            split3(v2, h[2], m[2], l[2]);
            split3(v3, h[3], m[3], l[3]);
            s = s + v0 * v0; s = s + v1 * v1; s = s + v2 * v2; s = s + v3 * v3;
            int kk = d >> 5, quad = (d >> 3) & 3, jb = d & 7;
            size_t base = (size_t)((gA * 3) * 8 + kk) * 512 + (quad * 16 + ml) * 8 + jb;
            *(ushort4*)&A2[base]        = make_ushort4(h[0], h[1], h[2], h[3]);
            *(ushort4*)&A2[base + 4096] = make_ushort4(m[0], m[1], m[2], m[3]);
            *(ushort4*)&A2[base + 8192] = make_ushort4(l[0], l[1], l[2], l[3]);
        }
        // An: sum the 4 q-partials (A-reorder safe: shifts all of a token's
        // distances by whole ulps uniformly; C < ulp/2 never changes rounding)
        s += __shfl_down(s, 1, 4);
        s += __shfl_down(s, 2, 4);
        if (q == 0) An[t] = s;
    }
}

// ---------------- kernel 2: bf16x3 MFMA distance GEMM + fused argmin ----------------
// R9 geometry: 256(M)x128(N) block tile, 4 waves of 64x128 stacked in M,
// 8 kk chunks of 32 k.  ZERO LDS, ZERO BARRIERS: both A and B fragments are
// loaded directly global->VGPR from the fragment-stream layouts (coalesced
// b128 per fragment).  The compiler is free to interleave buffer_load <-> MFMA
// with fine-grained vmcnt(N) -- no vmcnt(0) barrier drain (the R9 stall).
// Cross-wave B reuse within a block is caught by L1 (8 KB slice per (kk,q)).
// Load schedule and accumulation order bitwise identical to R9:
//   PP={0,1,2,0,1,0}, QQ={0,0,0,1,1,2} (bf once per q-group, af per t).
__global__ __launch_bounds__(256, 2) void vq_scores(const unsigned short* __restrict__ A2,
                                                    const unsigned short* __restrict__ B2,
                                                    const float* __restrict__ An,
                                                    const float* __restrict__ Cn,
                                                    unsigned long long* __restrict__ keys) {
    // 8x8 block-group swizzle over the 32(mt) x 64(nt) tile grid
    int bid = blockIdx.x;
    int g = bid >> 6, sl = bid & 63;
    int mt = (g >> 3) * 8 + (sl >> 3);    // 0..31
    int nt = (g & 7) * 8 + (sl & 7);      // 0..63
    const int token0 = mt * 256, code0 = nt * 128;

    const int wid = threadIdx.x >> 6, lane = threadIdx.x & 63;
    const int quad = lane >> 4, col = lane & 15;

    f32x4 acc[4][8];
    #pragma unroll
    for (int i = 0; i < 4; ++i)
        #pragma unroll
        for (int j = 0; j < 8; ++j) acc[i][j] = (f32x4){0.f, 0.f, 0.f, 0.f};

    const int gm0 = (token0 >> 4) + wid * 4;
    const int ngb = nt * 8;                   // first B n-group of this block
    const int PP[6] = {0, 1, 2, 0, 1, 0};     // A-part (loaded per t, R9 shape)
    const int QQ[6] = {0, 0, 0, 1, 1, 2};     // B-part (loaded once per q-group)

    for (int kk = 0; kk < 8; ++kk) {
        short8 bf[8];
        #pragma unroll
        for (int t = 0; t < 6; ++t) {
            const int p = PP[t], q = QQ[t];
            if (t == 0 || q != QQ[t - 1]) {       // B fragments: direct global b128
                #pragma unroll
                for (int j = 0; j < 8; ++j)
                    bf[j] = *(const short8*)&B2[(size_t)(((ngb + j) * 3 + q) * 8 + kk) * 512
                                                + lane * 8];
            }
            short8 af[4];
            #pragma unroll
            for (int i = 0; i < 4; ++i)           // A fragments: direct global b128
                af[i] = *(const short8*)&A2[(size_t)(((gm0 + i) * 3 + p) * 8 + kk) * 512
                                            + lane * 8];
            #pragma unroll
            for (int i = 0; i < 4; ++i)
                #pragma unroll
                for (int j = 0; j < 8; ++j)
                    acc[i][j] = __builtin_amdgcn_mfma_f32_16x16x32_bf16(
                        af[i], bf[j], acc[i][j], 0, 0, 0);
        }
    }

    // epilogue: dist = fl(fl(A - 2B) + C); argmin; C/D layout col=lane&15, row=quad*4+reg
    float cn[8]; int cidx[8];
    #pragma unroll
    for (int j = 0; j < 8; ++j) {
        cidx[j] = code0 + j * 16 + col;
        cn[j] = Cn[cidx[j]];
    }
    #pragma unroll
    for (int i = 0; i < 4; ++i) {
        #pragma unroll
        for (int r = 0; r < 4; ++r) {
            int token = token0 + wid * 64 + i * 16 + quad * 4 + r;
            float Ai = An[token];
            float bv = FLT_INF; int bi = 0;
            #pragma unroll
            for (int j = 0; j < 8; ++j) {
                float d1 = fmaf(-2.f, acc[i][j][r], Ai);   // fl(A-2B): 2B exact
                float dist = d1 + cn[j];                    // fl(+C)
                if (dist < bv) { bv = dist; bi = cidx[j]; }
            }
            #pragma unroll
            for (int off = 8; off; off >>= 1) {
                float ov = __shfl_down(bv, off, 16);
                int   oi = __shfl_down(bi, off, 16);
                if (ov < bv || (ov == bv && oi < bi)) { bv = ov; bi = oi; }
            }
            if (col == 0) {
                unsigned long long key =
                    ((unsigned long long)__float_as_uint(bv) << 32) | (unsigned)bi;
                atomicMin(&keys[token], key);
            }
        }
    }
}

// ---------------- kernel 3: gather z_q + ST out + indices + loss partial ----------------
__global__ __launch_bounds__(256) void vq_gather(const float* __restrict__ z,
                                                 const float* __restrict__ cb,
                                                 const unsigned long long* __restrict__ keys,
                                                 float* __restrict__ out,
                                                 float* __restrict__ out_idx,
                                                 float* __restrict__ loss_acc) {
    int e4 = blockIdx.x * 256 + threadIdx.x;     // float4 index, 524288 total
    int t4 = e4 & 255;
    int rest = e4 >> 8;
    int d = rest & 255;
    int b = rest >> 8;
    int gbase = b * 1024 + t4 * 4;

    const int* klo = (const int*)keys;           // low word of each u64 key = index
    int i0 = klo[(size_t)(gbase + 0) * 2];
    int i1 = klo[(size_t)(gbase + 1) * 2];
    int i2 = klo[(size_t)(gbase + 2) * 2];
    int i3 = klo[(size_t)(gbase + 3) * 2];
    if (d == 0) {
        out_idx[gbase + 0] = (float)i0;
        out_idx[gbase + 1] = (float)i1;
        out_idx[gbase + 2] = (float)i2;
        out_idx[gbase + 3] = (float)i3;
    }

    float4 zv = *(const float4*)&z[(size_t)e4 * 4];
    float q0 = cb[(size_t)i0 * DD + d];
    float q1 = cb[(size_t)i1 * DD + d];
    float q2 = cb[(size_t)i2 * DD + d];
    float q3 = cb[(size_t)i3 * DD + d];

    float d0 = q0 - zv.x, d1 = q1 - zv.y, d2 = q2 - zv.z, d3 = q3 - zv.w;
    float4 o;                                    // replicate z + (z_q - z) rounding
    o.x = zv.x + d0; o.y = zv.y + d1; o.z = zv.z + d2; o.w = zv.w + d3;
    *(float4*)&out[(size_t)e4 * 4] = o;

    float s = d0 * d0 + d1 * d1 + d2 * d2 + d3 * d3;
    #pragma unroll
    for (int off = 32; off; off >>= 1) s += __shfl_down(s, off, 64);
    __shared__ float wsum[4];
    if ((threadIdx.x & 63) == 0) wsum[threadIdx.x >> 6] = s;
    __syncthreads();
    if (threadIdx.x == 0)
        atomicAdd(loss_acc, wsum[0] + wsum[1] + wsum[2] + wsum[3]);
}

// ---------------- kernel 4: finalize loss ----------------
__global__ void vq_loss(const float* __restrict__ loss_acc, float* __restrict__ out_loss) {
    *out_loss = 1.25f * (*loss_acc) / 2097152.f;
}

extern "C" void kernel_launch(void* const* d_in, const int* in_sizes, int n_in,
                              void* d_out, int out_size, void* d_ws, size_t ws_size,
                              hipStream_t stream) {
    const float* z  = (const float*)d_in[0];
    const float* cb = (const float*)d_in[1];
    float* out = (float*)d_out;
    char*  w   = (char*)d_ws;

    unsigned short* A2 = (unsigned short*)(w + A2_B);
    unsigned short* B2 = (unsigned short*)(w + B2_B);
    float* An = (float*)(w + AN_B);
    float* Cn = (float*)(w + CN_B);
    unsigned long long* keys = (unsigned long long*)(w + KEY_B);
    float* lacc = (float*)(w + ACC_B);

    vq_prep   <<<2048 + 128, 256, 0, stream>>>(z, cb, An, A2, B2, Cn, keys, lacc);
    vq_scores <<<2048, 256, 0, stream>>>(A2, B2, An, Cn, keys);
    vq_gather <<<ZQ_SIZE / 1024, 256, 0, stream>>>(z, cb, keys, out, out + ZQ_SIZE, lacc);
    vq_loss   <<<1, 1, 0, stream>>>(lacc, out + ZQ_SIZE + BT);
}

// Round 14
// 262.149 us; speedup vs baseline: 1.1218x; 1.1218x over previous
//
#include <hip/hip_runtime.h>

#define DD   256
#define TT   1024
#define BT   8192
#define KK   8192
#define ZQ_SIZE 2097152

#define FLT_INF 3.402823466e38f

typedef __attribute__((ext_vector_type(8))) short short8;
typedef __attribute__((ext_vector_type(4))) float f32x4;

// ws layout (bytes)
// A2/B2: fragment-stream packing. 1024-B block per (16-row group, part, 32-k chunk):
//   short at blockbase + lane*8 + j holds X[row = grp*16 + (lane&15)][k = kk*32 + (lane>>4)*8 + j]
// A2[g 0..511][p 0..2][kk 0..7] ; B2[ng 0..511][p][kk]
#define A2_B    0u           // 512*3*8*1024 = 12582912 B
#define B2_B    12582912u
#define AN_B    25165824u    // An: 8192 f32
#define CN_B    25198592u    // Cn: 8192 f32
#define KEY_B   25231360u    // keys: 8192 u64
#define ACC_B   25296896u    // loss acc: 1 f32

static __device__ __forceinline__ unsigned short f2bf(float x) {  // RNE fp32->bf16
    unsigned int u = __float_as_uint(x);
    return (unsigned short)((u + 0x7FFF + ((u >> 16) & 1)) >> 16);
}
static __device__ __forceinline__ float bf2f(unsigned short h) {
    return __uint_as_float(((unsigned int)h) << 16);
}
// exact 3-term split: x == h + m + l (each difference exact in fp32)
static __device__ __forceinline__ void split3(float x, unsigned short& h,
                                              unsigned short& m, unsigned short& l) {
    h = f2bf(x);
    float r1 = x - bf2f(h);
    m = f2bf(r1);
    l = f2bf(r1 - bf2f(m));
}

static __device__ __forceinline__ void gld16(const void* g, const void* l) {
    __builtin_amdgcn_global_load_lds(
        (const __attribute__((address_space(1))) unsigned int*)g,
        (__attribute__((address_space(3))) unsigned int*)l, 16, 0, 0);
}

// ---------------- kernel 1: fused prep ----------------
// blocks 0..2047:    B2 frag-pack + Cn + keys/lacc init
// blocks 2048..2175: A2 frag-pack (via LDS transpose) + An (token norms)
__global__ __launch_bounds__(256) void vq_prep(const float* __restrict__ z,
                                               const float* __restrict__ cb,
                                               float* __restrict__ An,
                                               unsigned short* __restrict__ A2,
                                               unsigned short* __restrict__ B2,
                                               float* __restrict__ Cn,
                                               unsigned long long* __restrict__ keys,
                                               float* __restrict__ lacc) {
    __shared__ float T[64][257];
    int tid = threadIdx.x;
    if (blockIdx.x < 2048) {
        // B2: cb -> fragment-stream packing ; Cn fused ; keys init fused
        int g = blockIdx.x * 256 + tid;              // 0..524287
        int code = g >> 6, d4 = (g & 63) * 4;
        if (d4 == 0) {
            keys[code] = ~0ull;
            if (code == 0) *lacc = 0.f;
        }
        float4 v = *(const float4*)&cb[(size_t)code * DD + d4];
        unsigned short h[4], m[4], l[4];
        split3(v.x, h[0], m[0], l[0]);
        split3(v.y, h[1], m[1], l[1]);
        split3(v.z, h[2], m[2], l[2]);
        split3(v.w, h[3], m[3], l[3]);
        int ng = code >> 4;
        int lane = ((d4 >> 3) & 3) * 16 + (code & 15);
        int kk = d4 >> 5;
        int jb = d4 & 7;                             // 0 or 4
        size_t base = (size_t)((ng * 3) * 8 + kk) * 512 + lane * 8 + jb;
        *(ushort4*)&B2[base]        = make_ushort4(h[0], h[1], h[2], h[3]);
        *(ushort4*)&B2[base + 4096] = make_ushort4(m[0], m[1], m[2], m[3]);
        *(ushort4*)&B2[base + 8192] = make_ushort4(l[0], l[1], l[2], l[3]);
        float s = v.x * v.x + v.y * v.y + v.z * v.z + v.w * v.w;
        #pragma unroll
        for (int off = 32; off; off >>= 1) s += __shfl_down(s, off, 64);
        if ((tid & 63) == 0) Cn[code] = s;
    } else {
        // A2 via LDS transpose: z[b,d,t] -> frag-stream packing ; An fused
        int blk = blockIdx.x - 2048;                 // 0..127
        int b = blk >> 4;
        int t0 = (blk & 15) * 64;
        #pragma unroll
        for (int it = 0; it < 16; ++it) {
            int d = it * 16 + (tid >> 4);
            int t4 = (tid & 15) * 4;
            float4 v = *(const float4*)&z[(size_t)b * (DD * TT) + (size_t)d * TT + t0 + t4];
            T[t4 + 0][d] = v.x; T[t4 + 1][d] = v.y; T[t4 + 2][d] = v.z; T[t4 + 3][d] = v.w;
        }
        __syncthreads();
        int r = tid >> 2, q = tid & 3;
        int t = b * 1024 + t0 + r;
        int gA = t >> 4, ml = t & 15;
        float s = 0.f;
        #pragma unroll
        for (int dd = 0; dd < 16; ++dd) {
            int d = dd * 16 + q * 4;
            float v0 = T[r][d], v1 = T[r][d + 1], v2 = T[r][d + 2], v3 = T[r][d + 3];
            unsigned short h[4], m[4], l[4];
            split3(v0, h[0], m[0], l[0]);
            split3(v1, h[1], m[1], l[1]);
            split3(v2, h[2], m[2], l[2]);
            split3(v3, h[3], m[3], l[3]);
            s = s + v0 * v0; s = s + v1 * v1; s = s + v2 * v2; s = s + v3 * v3;
            int kk = d >> 5, quad = (d >> 3) & 3, jb = d & 7;
            size_t base = (size_t)((gA * 3) * 8 + kk) * 512 + (quad * 16 + ml) * 8 + jb;
            *(ushort4*)&A2[base]        = make_ushort4(h[0], h[1], h[2], h[3]);
            *(ushort4*)&A2[base + 4096] = make_ushort4(m[0], m[1], m[2], m[3]);
            *(ushort4*)&A2[base + 8192] = make_ushort4(l[0], l[1], l[2], l[3]);
        }
        // An: sum the 4 q-partials (A-reorder safe: shifts all of a token's
        // distances by whole ulps uniformly; C < ulp/2 never changes rounding)
        s += __shfl_down(s, 1, 4);
        s += __shfl_down(s, 2, 4);
        if (q == 0) An[t] = s;
    }
}

// ---------------- kernel 2: bf16x3 MFMA distance GEMM + fused argmin ----------------
// R9 geometry (best measured: 174 us): 256(M)x128(N) block tile, 4 waves of
// 64x128 stacked in M, 8 kk chunks of 32 k, B double-buffered LDS (2x24 KB),
// A direct global.  PP={0,1,2,0,1,0}, QQ={0,0,0,1,1,2}.
// NEW vs R9: explicit af double-buffering -- af(t+1) is loaded BEFORE the
// 32-MFMA group of step t, so the VMEM latency of 5 of the 6 af-loads per kk
// hides under MFMA wave-time.  MFMA sequence unchanged -> bitwise-identical.
__global__ __launch_bounds__(256, 2) void vq_scores(const unsigned short* __restrict__ A2,
                                                    const unsigned short* __restrict__ B2,
                                                    const float* __restrict__ An,
                                                    const float* __restrict__ Cn,
                                                    unsigned long long* __restrict__ keys) {
    __shared__ __attribute__((aligned(16))) unsigned short Bl[2][12288];   // 2 x 24 KB

    // 8x8 block-group swizzle over the 32(mt) x 64(nt) tile grid
    int bid = blockIdx.x;
    int g = bid >> 6, sl = bid & 63;
    int mt = (g >> 3) * 8 + (sl >> 3);    // 0..31
    int nt = (g & 7) * 8 + (sl & 7);      // 0..63
    const int token0 = mt * 256, code0 = nt * 128;

    const int wid = threadIdx.x >> 6, lane = threadIdx.x & 63;
    const int quad = lane >> 4, col = lane & 15;

    // staging: 24 x 1KB frag blocks per kk (8 n-groups x 3 parts); wave does 6
    int sidx[6]; size_t soff[6];
    #pragma unroll
    for (int n = 0; n < 6; ++n) {
        int idx = wid * 6 + n;            // 0..23
        int p = idx >> 3, ngl = idx & 7;
        sidx[n] = idx * 512;              // LDS short offset (HW adds lane*16 B)
        soff[n] = (size_t)(((nt * 8 + ngl) * 3 + p) * 8) * 512 + lane * 8;
    }

    f32x4 acc[4][8];
    #pragma unroll
    for (int i = 0; i < 4; ++i)
        #pragma unroll
        for (int j = 0; j < 8; ++j) acc[i][j] = (f32x4){0.f, 0.f, 0.f, 0.f};

    // prologue: stage kk=0 -> buf 0
    #pragma unroll
    for (int n = 0; n < 6; ++n)
        gld16(B2 + soff[n], &Bl[0][sidx[n]]);

    const int gm0 = (token0 >> 4) + wid * 4;
    const int PP[6] = {0, 1, 2, 0, 1, 0};     // A-part
    const int QQ[6] = {0, 0, 0, 1, 1, 2};     // B-part (p+q<=2: exact 6-term schedule)

    for (int kk = 0; kk < 8; ++kk) {
        __syncthreads();   // drains buf[kk&1] gld16 (issued a full kk ago); prev readers done
        if (kk < 7) {      // prefetch kk+1 into the other buffer
            #pragma unroll
            for (int n = 0; n < 6; ++n)
                gld16(B2 + soff[n] + (size_t)(kk + 1) * 512, &Bl[(kk + 1) & 1][sidx[n]]);
        }
        const unsigned short* B = Bl[kk & 1];
        short8 bf[8], afc[4], afn[4];
        #pragma unroll
        for (int i = 0; i < 4; ++i)           // af for t=0 (p=0)
            afc[i] = *(const short8*)&A2[(size_t)(((gm0 + i) * 3 + 0) * 8 + kk) * 512
                                         + lane * 8];
        #pragma unroll
        for (int t = 0; t < 6; ++t) {
            const int p = PP[t], q = QQ[t];
            (void)p;
            if (t == 0 || q != QQ[t - 1]) {       // load B-part fragments (linear LDS)
                #pragma unroll
                for (int j = 0; j < 8; ++j)
                    bf[j] = *(const short8*)&B[(q * 8 + j) * 512 + lane * 8];
            }
            if (t < 5) {                          // prefetch af(t+1) before MFMA group t
                const int pn = PP[t + 1];
                #pragma unroll
                for (int i = 0; i < 4; ++i)
                    afn[i] = *(const short8*)&A2[(size_t)(((gm0 + i) * 3 + pn) * 8 + kk) * 512
                                                 + lane * 8];
            }
            #pragma unroll
            for (int i = 0; i < 4; ++i)
                #pragma unroll
                for (int j = 0; j < 8; ++j)
                    acc[i][j] = __builtin_amdgcn_mfma_f32_16x16x32_bf16(
                        afc[i], bf[j], acc[i][j], 0, 0, 0);
            if (t < 5) {
                #pragma unroll
                for (int i = 0; i < 4; ++i) afc[i] = afn[i];   // register rename (free)
            }
        }
    }

    // epilogue: dist = fl(fl(A - 2B) + C); argmin; C/D layout col=lane&15, row=quad*4+reg
    float cn[8]; int cidx[8];
    #pragma unroll
    for (int j = 0; j < 8; ++j) {
        cidx[j] = code0 + j * 16 + col;
        cn[j] = Cn[cidx[j]];
    }
    #pragma unroll
    for (int i = 0; i < 4; ++i) {
        #pragma unroll
        for (int r = 0; r < 4; ++r) {
            int token = token0 + wid * 64 + i * 16 + quad * 4 + r;
            float Ai = An[token];
            float bv = FLT_INF; int bi = 0;
            #pragma unroll
            for (int j = 0; j < 8; ++j) {
                float d1 = fmaf(-2.f, acc[i][j][r], Ai);   // fl(A-2B): 2B exact
                float dist = d1 + cn[j];                    // fl(+C)
                if (dist < bv) { bv = dist; bi = cidx[j]; }
            }
            #pragma unroll
            for (int off = 8; off; off >>= 1) {
                float ov = __shfl_down(bv, off, 16);
                int   oi = __shfl_down(bi, off, 16);
                if (ov < bv || (ov == bv && oi < bi)) { bv = ov; bi = oi; }
            }
            if (col == 0) {
                unsigned long long key =
                    ((unsigned long long)__float_as_uint(bv) << 32) | (unsigned)bi;
                atomicMin(&keys[token], key);
            }
        }
    }
}

// ---------------- kernel 3: gather z_q + ST out + indices + loss partial ----------------
__global__ __launch_bounds__(256) void vq_gather(const float* __restrict__ z,
                                                 const float* __restrict__ cb,
                                                 const unsigned long long* __restrict__ keys,
                                                 float* __restrict__ out,
                                                 float* __restrict__ out_idx,
                                                 float* __restrict__ loss_acc) {
    int e4 = blockIdx.x * 256 + threadIdx.x;     // float4 index, 524288 total
    int t4 = e4 & 255;
    int rest = e4 >> 8;
    int d = rest & 255;
    int b = rest >> 8;
    int gbase = b * 1024 + t4 * 4;

    const int* klo = (const int*)keys;           // low word of each u64 key = index
    int i0 = klo[(size_t)(gbase + 0) * 2];
    int i1 = klo[(size_t)(gbase + 1) * 2];
    int i2 = klo[(size_t)(gbase + 2) * 2];
    int i3 = klo[(size_t)(gbase + 3) * 2];
    if (d == 0) {
        out_idx[gbase + 0] = (float)i0;
        out_idx[gbase + 1] = (float)i1;
        out_idx[gbase + 2] = (float)i2;
        out_idx[gbase + 3] = (float)i3;
    }

    float4 zv = *(const float4*)&z[(size_t)e4 * 4];
    float q0 = cb[(size_t)i0 * DD + d];
    float q1 = cb[(size_t)i1 * DD + d];
    float q2 = cb[(size_t)i2 * DD + d];
    float q3 = cb[(size_t)i3 * DD + d];

    float d0 = q0 - zv.x, d1 = q1 - zv.y, d2 = q2 - zv.z, d3 = q3 - zv.w;
    float4 o;                                    // replicate z + (z_q - z) rounding
    o.x = zv.x + d0; o.y = zv.y + d1; o.z = zv.z + d2; o.w = zv.w + d3;
    *(float4*)&out[(size_t)e4 * 4] = o;

    float s = d0 * d0 + d1 * d1 + d2 * d2 + d3 * d3;
    #pragma unroll
    for (int off = 32; off; off >>= 1) s += __shfl_down(s, off, 64);
    __shared__ float wsum[4];
    if ((threadIdx.x & 63) == 0) wsum[threadIdx.x >> 6] = s;
    __syncthreads();
    if (threadIdx.x == 0)
        atomicAdd(loss_acc, wsum[0] + wsum[1] + wsum[2] + wsum[3]);
}

// ---------------- kernel 4: finalize loss ----------------
__global__ void vq_loss(const float* __restrict__ loss_acc, float* __restrict__ out_loss) {
    *out_loss = 1.25f * (*loss_acc) / 2097152.f;
}

extern "C" void kernel_launch(void* const* d_in, const int* in_sizes, int n_in,
                              void* d_out, int out_size, void* d_ws, size_t ws_size,
                              hipStream_t stream) {
    const float* z  = (const float*)d_in[0];
    const float* cb = (const float*)d_in[1];
    float* out = (float*)d_out;
    char*  w   = (char*)d_ws;

    unsigned short* A2 = (unsigned short*)(w + A2_B);
    unsigned short* B2 = (unsigned short*)(w + B2_B);
    float* An = (float*)(w + AN_B);
    float* Cn = (float*)(w + CN_B);
    unsigned long long* keys = (unsigned long long*)(w + KEY_B);
    float* lacc = (float*)(w + ACC_B);

    vq_prep   <<<2048 + 128, 256, 0, stream>>>(z, cb, An, A2, B2, Cn, keys, lacc);
    vq_scores <<<2048, 256, 0, stream>>>(A2, B2, An, Cn, keys);
    vq_gather <<<ZQ_SIZE / 1024, 256, 0, stream>>>(z, cb, keys, out, out + ZQ_SIZE, lacc);
    vq_loss   <<<1, 1, 0, stream>>>(lacc, out + ZQ_SIZE + BT);
}